// Round 9
// baseline (56.685 us; speedup 1.0000x reference)
//
#include <hip/hip_runtime.h>
#include <math.h>

#define B_DIM 4096
#define L_DIM 512
#define N_DIM 1024

// -half*log(2): exact value of each term once P has fully underflowed to zero.
#define NEG_HALF_LOG2 (-0.34657359027997264f)

typedef float f32x2 __attribute__((ext_vector_type(2)));
typedef float f32x4 __attribute__((ext_vector_type(4)));
#define VLO(v) __builtin_shufflevector(v, v, 0, 1)
#define VHI(v) __builtin_shufflevector(v, v, 2, 3)

// Select component k (compile-time) of an 8-index chunk held in two int4s.
#define SEL8(k, A, B) ((k) == 0 ? (A).x : (k) == 1 ? (A).y : (k) == 2 ? (A).z \
                     : (k) == 3 ? (A).w : (k) == 4 ? (B).x : (k) == 5 ? (B).y \
                     : (k) == 6 ? (B).z : (B).w)

// ---------------------------------------------------------------------------
// Packed fp32 ops (VOP3P), 2x the scalar v_fma_f32 rate on CDNA4.
// ---------------------------------------------------------------------------
__device__ __forceinline__ f32x2 pk_fma(f32x2 a, f32x2 b, f32x2 c) {
    f32x2 d;
    asm("v_pk_fma_f32 %0, %1, %2, %3" : "=v"(d) : "v"(a), "v"(b), "v"(c));
    return d;
}
__device__ __forceinline__ f32x2 pk_mul(f32x2 a, f32x2 b) {
    f32x2 d;
    asm("v_pk_mul_f32 %0, %1, %2" : "=v"(d) : "v"(a), "v"(b));
    return d;
}
__device__ __forceinline__ f32x2 pk_add(f32x2 a, f32x2 b) {
    f32x2 d;
    asm("v_pk_add_f32 %0, %1, %2" : "=v"(d) : "v"(a), "v"(b));
    return d;
}

// ---------------------------------------------------------------------------
// Kernel A: transpose eps (2, N, L) -> epsT (L, 2, N).
// ---------------------------------------------------------------------------
__global__ void transpose_eps(const float* __restrict__ eps,
                              float* __restrict__ epsT) {
    __shared__ float tile[32][33];
    const int s  = blockIdx.z;
    const int i0 = blockIdx.x * 32;
    const int n0 = blockIdx.y * 32;
    const int tx = threadIdx.x;
    const int ty = threadIdx.y;
#pragma unroll
    for (int k = 0; k < 32; k += 8) {
        tile[ty + k][tx] =
            eps[((size_t)s * N_DIM + (size_t)(n0 + ty + k)) * L_DIM + (i0 + tx)];
    }
    __syncthreads();
#pragma unroll
    for (int k = 0; k < 32; k += 8) {
        epsT[(size_t)(i0 + ty + k) * (2 * N_DIM) + (size_t)s * N_DIM + (n0 + tx)] =
            tile[tx][ty + k];
    }
}

// ---------------------------------------------------------------------------
// DPP wave-64 sum; lane 63 ends with the full sum. All VALU-pipe.
// ---------------------------------------------------------------------------
template <int CTRL>
__device__ __forceinline__ float dpp_add(float x) {
    int v = __builtin_amdgcn_update_dpp(0, __float_as_int(x), CTRL, 0xf, 0xf, true);
    return x + __int_as_float(v);
}
__device__ __forceinline__ float wave_sum63(float x) {
    x = dpp_add<0x111>(x);  // row_shr:1
    x = dpp_add<0x112>(x);  // row_shr:2
    x = dpp_add<0x114>(x);  // row_shr:4
    x = dpp_add<0x118>(x);  // row_shr:8
    x = dpp_add<0x142>(x);  // row_bcast:15
    x = dpp_add<0x143>(x);  // row_bcast:31
    return x;
}
__device__ __forceinline__ float read63(float x) {
    return __int_as_float(__builtin_amdgcn_readlane(__float_as_int(x), 63));
}

// ---------------------------------------------------------------------------
// Main kernel: 256-thread blocks (4 waves), each wave owns FOUR rows ->
// 16 rows/block, 256 blocks = 1 block/CU. The 8 KB eps slice is staged once
// per block into double-buffered LDS; each wave's 8 ds_read_b128/lane/step
// now serve 4 rows (per-row read cost halved vs R=2 — the r8 counters showed
// the LDS/L1 read pipe, not cache BW and not VALU issue, is the wall).
// Collectors: row r step k -> lane 8r+k; batched logsumexp tail across lanes
// 0..31 once per 8-step chunk. Block-wide early-exit vote per chunk (dead
// rows contribute exactly -1/2*log2, so overshoot is exact).
// ---------------------------------------------------------------------------
__global__ __launch_bounds__(256, 1) void arqgps_lds4(
    const int* __restrict__ indices,
    const float* __restrict__ epsT,   // (L, 2, N)
    float* __restrict__ out)
{
    const int tid   = threadIdx.x;
    const int lane  = tid & 63;
    const int wave  = __builtin_amdgcn_readfirstlane(tid >> 6);  // 0..3
    const int bb    = blockIdx.x * 16 + wave * 4;
    const int lane4 = lane * 4;

    const int* ip0 = indices + (size_t)(bb + 0) * L_DIM;
    const int* ip1 = indices + (size_t)(bb + 1) * L_DIM;
    const int* ip2 = indices + (size_t)(bb + 2) * L_DIM;
    const int* ip3 = indices + (size_t)(bb + 3) * L_DIM;

    __shared__ float sbuf[2][2 * N_DIM];   // 2 x 8 KB double buffer

    // Prime: stage slice 0 into buffer 0 (256 threads x 2 f32x4 = 8 KB).
    *(f32x4*)&sbuf[0][tid * 4]        = *(const f32x4*)(epsT + tid * 4);
    *(f32x4*)&sbuf[0][1024 + tid * 4] = *(const f32x4*)(epsT + 1024 + tid * 4);
    __syncthreads();

    f32x2 P[4][8];
#pragma unroll
    for (int r = 0; r < 4; ++r)
#pragma unroll
        for (int c = 0; c < 8; ++c) P[r][c] = (f32x2){1.0f, 1.0f};

    float vacc = 0.0f;   // batched-tail accumulator (lanes 0..31 live)
    float uacc = 0.0f;   // uniform early-exit remainder
    float collA = 0.0f, collB = 0.0f;

    for (int i0 = 0; i0 < L_DIM; i0 += 8) {
        const int4 sA0 = *(const int4*)(ip0 + i0);
        const int4 sB0 = *(const int4*)(ip0 + i0 + 4);
        const int4 sA1 = *(const int4*)(ip1 + i0);
        const int4 sB1 = *(const int4*)(ip1 + i0 + 4);
        const int4 sA2 = *(const int4*)(ip2 + i0);
        const int4 sB2 = *(const int4*)(ip2 + i0 + 4);
        const int4 sA3 = *(const int4*)(ip3 + i0);
        const int4 sB3 = *(const int4*)(ip3 + i0 + 4);
        int sm0 = 0, sm1 = 0, sm2 = 0, sm3 = 0;
#pragma unroll
        for (int k = 0; k < 8; ++k) {
            const int i   = i0 + k;
            const int cur = i & 1;

            // Issue next-slice global load early (hidden under compute).
            const int inext = (i + 1 < L_DIM) ? (i + 1) : (L_DIM - 1);
            const float* gnext = epsT + (size_t)inext * (2 * N_DIM);
            const f32x4 stg0 = *(const f32x4*)(gnext + tid * 4);
            const f32x4 stg1 = *(const f32x4*)(gnext + 1024 + tid * 4);

            // Read this step's slice from LDS (8 ds_read_b128/lane, serves
            // all 4 rows).
            const float* e = &sbuf[cur][0];
            f32x4 e0q[4], e1q[4];
#pragma unroll
            for (int c = 0; c < 4; ++c) {
                e0q[c] = *(const f32x4*)(e + c * 256 + lane4);
                e1q[c] = *(const f32x4*)(e + N_DIM + c * 256 + lane4);
            }

            // Dots for 4 rows x 2 slices; 8 DPP reduces (chains interleave).
            float X0[4], X1[4];
#pragma unroll
            for (int r = 0; r < 4; ++r) {
                f32x2 u0 = {0.f, 0.f}, u1 = {0.f, 0.f};
                f32x2 v0 = {0.f, 0.f}, v1 = {0.f, 0.f};
#pragma unroll
                for (int c = 0; c < 4; ++c) {
                    u0 = pk_fma(VLO(e0q[c]), P[r][2 * c],     u0);
                    u1 = pk_fma(VHI(e0q[c]), P[r][2 * c + 1], u1);
                    v0 = pk_fma(VLO(e1q[c]), P[r][2 * c],     v0);
                    v1 = pk_fma(VHI(e1q[c]), P[r][2 * c + 1], v1);
                }
                const f32x2 tu = pk_add(u0, u1);
                const f32x2 tv = pk_add(v0, v1);
                X0[r] = read63(wave_sum63(tu.x + tu.y));
                X1[r] = read63(wave_sum63(tv.x + tv.y));
            }

            // Collect: row r step k -> lane 8r+k.
#pragma unroll
            for (int r = 0; r < 4; ++r) {
                const bool isk = (lane == 8 * r + k);
                collA = isk ? X0[r] : collA;
                collB = isk ? X1[r] : collB;
            }

            const int s0 = __builtin_amdgcn_readfirstlane(SEL8(k, sA0, sB0));
            const int s1 = __builtin_amdgcn_readfirstlane(SEL8(k, sA1, sB1));
            const int s2 = __builtin_amdgcn_readfirstlane(SEL8(k, sA2, sB2));
            const int s3 = __builtin_amdgcn_readfirstlane(SEL8(k, sA3, sB3));
            sm0 |= (s0 << k);
            sm1 |= (s1 << k);
            sm2 |= (s2 << k);
            sm3 |= (s3 << k);

            // P updates per row under wave-uniform scalar branches.
            if (s0) {
#pragma unroll
                for (int c = 0; c < 4; ++c) {
                    P[0][2 * c]     = pk_mul(P[0][2 * c],     VLO(e1q[c]));
                    P[0][2 * c + 1] = pk_mul(P[0][2 * c + 1], VHI(e1q[c]));
                }
            } else {
#pragma unroll
                for (int c = 0; c < 4; ++c) {
                    P[0][2 * c]     = pk_mul(P[0][2 * c],     VLO(e0q[c]));
                    P[0][2 * c + 1] = pk_mul(P[0][2 * c + 1], VHI(e0q[c]));
                }
            }
            if (s1) {
#pragma unroll
                for (int c = 0; c < 4; ++c) {
                    P[1][2 * c]     = pk_mul(P[1][2 * c],     VLO(e1q[c]));
                    P[1][2 * c + 1] = pk_mul(P[1][2 * c + 1], VHI(e1q[c]));
                }
            } else {
#pragma unroll
                for (int c = 0; c < 4; ++c) {
                    P[1][2 * c]     = pk_mul(P[1][2 * c],     VLO(e0q[c]));
                    P[1][2 * c + 1] = pk_mul(P[1][2 * c + 1], VHI(e0q[c]));
                }
            }
            if (s2) {
#pragma unroll
                for (int c = 0; c < 4; ++c) {
                    P[2][2 * c]     = pk_mul(P[2][2 * c],     VLO(e1q[c]));
                    P[2][2 * c + 1] = pk_mul(P[2][2 * c + 1], VHI(e1q[c]));
                }
            } else {
#pragma unroll
                for (int c = 0; c < 4; ++c) {
                    P[2][2 * c]     = pk_mul(P[2][2 * c],     VLO(e0q[c]));
                    P[2][2 * c + 1] = pk_mul(P[2][2 * c + 1], VHI(e0q[c]));
                }
            }
            if (s3) {
#pragma unroll
                for (int c = 0; c < 4; ++c) {
                    P[3][2 * c]     = pk_mul(P[3][2 * c],     VLO(e1q[c]));
                    P[3][2 * c + 1] = pk_mul(P[3][2 * c + 1], VHI(e1q[c]));
                }
            } else {
#pragma unroll
                for (int c = 0; c < 4; ++c) {
                    P[3][2 * c]     = pk_mul(P[3][2 * c],     VLO(e0q[c]));
                    P[3][2 * c + 1] = pk_mul(P[3][2 * c + 1], VHI(e0q[c]));
                }
            }

            // Commit staged slice i+1 into the other buffer; the barrier
            // gates both "stage visible" and "reads of cur^1 complete".
            *(f32x4*)&sbuf[cur ^ 1][tid * 4]        = stg0;
            *(f32x4*)&sbuf[cur ^ 1][1024 + tid * 4] = stg1;
            __syncthreads();
        }

        // Batched tail: lane 8r+k -> row r, step i0+k.
        {
            const float Av = collA, Bv = collB;
            const int g  = (lane >> 3) & 3;
            const int sm = (g == 0) ? sm0 : (g == 1) ? sm1 : (g == 2) ? sm2 : sm3;
            const int kk = lane & 7;
            const int sb = (sm >> kk) & 1;
            const float xs = sb ? Bv : Av;
            const float m  = fmaxf(Av, Bv);
            const float d  = fabsf(Av - Bv);
            const float c  = (xs - m) - 0.5f * __logf(1.0f + __expf(-2.0f * d));
            vacc += (lane < 32) ? c : 0.0f;
        }

        // Block-wide all-|P|-zero vote once per 8 steps.
        float mx = 0.f;
#pragma unroll
        for (int r = 0; r < 4; ++r)
#pragma unroll
            for (int c = 0; c < 8; ++c)
                mx = fmaxf(mx, fmaxf(fabsf(P[r][c].x), fabsf(P[r][c].y)));
        if (!__syncthreads_or(mx > 0.0f)) {
            uacc = (float)(L_DIM - 8 - i0) * NEG_HALF_LOG2;
            break;
        }
    }

    // Per-row sums: butterfly within each 8-lane group; lane 8r writes row r.
    float s = vacc;
    s += __shfl_xor(s, 1, 64);
    s += __shfl_xor(s, 2, 64);
    s += __shfl_xor(s, 4, 64);
    if ((lane & 7) == 0 && lane < 32) out[bb + (lane >> 3)] = s + uacc;
}

// ---------------------------------------------------------------------------
// Fallback (no workspace): round-7 per-wave kernel reading eps strided.
// ---------------------------------------------------------------------------
__global__ __launch_bounds__(512, 2) void arqgps_fallback(
    const int* __restrict__ indices,
    const float* __restrict__ eps,    // (2, N, L)
    float* __restrict__ out)
{
    const int lane  = threadIdx.x & 63;
    const int wave  = __builtin_amdgcn_readfirstlane((int)(threadIdx.x >> 6));
    const int b0    = (blockIdx.x * 8 + wave) * 2;
    const int b1    = b0 + 1;
    const int lane4 = lane * 4;
    const int* idx0 = indices + (size_t)b0 * L_DIM;
    const int* idx1 = indices + (size_t)b1 * L_DIM;

    f32x2 P0[8], P1[8];
#pragma unroll
    for (int c = 0; c < 8; ++c) {
        P0[c] = (f32x2){1.0f, 1.0f};
        P1[c] = (f32x2){1.0f, 1.0f};
    }
    float vacc = 0.0f, uacc = 0.0f, collA = 0.0f, collB = 0.0f;

    for (int i0 = 0; i0 < L_DIM; i0 += 8) {
        const int4 sA0 = *(const int4*)(idx0 + i0);
        const int4 sB0 = *(const int4*)(idx0 + i0 + 4);
        const int4 sA1 = *(const int4*)(idx1 + i0);
        const int4 sB1 = *(const int4*)(idx1 + i0 + 4);
        int smask0 = 0, smask1 = 0;
#pragma unroll
        for (int k = 0; k < 8; ++k) {
            const int i = i0 + k;
            f32x4 e0q[4], e1q[4];
#pragma unroll
            for (int c = 0; c < 4; ++c) {
                const int n = c * 256 + lane4;
                f32x4 t0, t1;
#pragma unroll
                for (int j = 0; j < 4; ++j) {
                    t0[j] = eps[(size_t)(n + j) * L_DIM + i];
                    t1[j] = eps[((size_t)N_DIM + n + j) * L_DIM + i];
                }
                e0q[c] = t0; e1q[c] = t1;
            }
            f32x2 a00 = {0.f, 0.f}, a01 = {0.f, 0.f};
            f32x2 a10 = {0.f, 0.f}, a11 = {0.f, 0.f};
            f32x2 c00 = {0.f, 0.f}, c01 = {0.f, 0.f};
            f32x2 c10 = {0.f, 0.f}, c11 = {0.f, 0.f};
#pragma unroll
            for (int c = 0; c < 4; ++c) {
                const f32x2 lo0 = VLO(e0q[c]), hi0 = VHI(e0q[c]);
                const f32x2 lo1 = VLO(e1q[c]), hi1 = VHI(e1q[c]);
                a00 = pk_fma(lo0, P0[2 * c],     a00);
                a01 = pk_fma(hi0, P0[2 * c + 1], a01);
                a10 = pk_fma(lo1, P0[2 * c],     a10);
                a11 = pk_fma(hi1, P0[2 * c + 1], a11);
                c00 = pk_fma(lo0, P1[2 * c],     c00);
                c01 = pk_fma(hi0, P1[2 * c + 1], c01);
                c10 = pk_fma(lo1, P1[2 * c],     c10);
                c11 = pk_fma(hi1, P1[2 * c + 1], c11);
            }
            const f32x2 r0x0 = pk_add(a00, a01);
            const f32x2 r0x1 = pk_add(a10, a11);
            const f32x2 r1x0 = pk_add(c00, c01);
            const f32x2 r1x1 = pk_add(c10, c11);
            const float X00 = read63(wave_sum63(r0x0.x + r0x0.y));
            const float X01 = read63(wave_sum63(r0x1.x + r0x1.y));
            const float X10 = read63(wave_sum63(r1x0.x + r1x0.y));
            const float X11 = read63(wave_sum63(r1x1.x + r1x1.y));
            const bool isk0 = (lane == k);
            const bool isk1 = (lane == k + 8);
            collA = isk0 ? X00 : (isk1 ? X10 : collA);
            collB = isk0 ? X01 : (isk1 ? X11 : collB);
            const int s0 = __builtin_amdgcn_readfirstlane(SEL8(k, sA0, sB0));
            const int s1 = __builtin_amdgcn_readfirstlane(SEL8(k, sA1, sB1));
            smask0 |= (s0 << k);
            smask1 |= (s1 << k);
            if (s0) {
#pragma unroll
                for (int c = 0; c < 4; ++c) {
                    P0[2 * c]     = pk_mul(P0[2 * c],     VLO(e1q[c]));
                    P0[2 * c + 1] = pk_mul(P0[2 * c + 1], VHI(e1q[c]));
                }
            } else {
#pragma unroll
                for (int c = 0; c < 4; ++c) {
                    P0[2 * c]     = pk_mul(P0[2 * c],     VLO(e0q[c]));
                    P0[2 * c + 1] = pk_mul(P0[2 * c + 1], VHI(e0q[c]));
                }
            }
            if (s1) {
#pragma unroll
                for (int c = 0; c < 4; ++c) {
                    P1[2 * c]     = pk_mul(P1[2 * c],     VLO(e1q[c]));
                    P1[2 * c + 1] = pk_mul(P1[2 * c + 1], VHI(e1q[c]));
                }
            } else {
#pragma unroll
                for (int c = 0; c < 4; ++c) {
                    P1[2 * c]     = pk_mul(P1[2 * c],     VLO(e0q[c]));
                    P1[2 * c + 1] = pk_mul(P1[2 * c + 1], VHI(e0q[c]));
                }
            }
        }
        {
            const float Av = collA, Bv = collB;
            const int   kk = lane & 7;
            const int   sm = (lane < 8) ? smask0 : smask1;
            const int   sb = (sm >> kk) & 1;
            const float xs = sb ? Bv : Av;
            const float m  = fmaxf(Av, Bv);
            const float d  = fabsf(Av - Bv);
            const float c  = (xs - m) - 0.5f * __logf(1.0f + __expf(-2.0f * d));
            vacc += (lane < 16) ? c : 0.0f;
        }
        float mx = 0.f;
#pragma unroll
        for (int c = 0; c < 8; ++c) {
            mx = fmaxf(mx, fmaxf(fabsf(P0[c].x), fabsf(P0[c].y)));
            mx = fmaxf(mx, fmaxf(fabsf(P1[c].x), fabsf(P1[c].y)));
        }
        if (!__any(mx > 0.0f)) {
            uacc = (float)(L_DIM - 8 - i0) * NEG_HALF_LOG2;
            break;
        }
    }
    float s = vacc;
    s += __shfl_xor(s, 1, 64);
    s += __shfl_xor(s, 2, 64);
    s += __shfl_xor(s, 4, 64);
    if (lane == 0) out[b0] = s + uacc;
    if (lane == 8) out[b1] = s + uacc;
}

extern "C" void kernel_launch(void* const* d_in, const int* in_sizes, int n_in,
                              void* d_out, int out_size, void* d_ws, size_t ws_size,
                              hipStream_t stream) {
    const int*   indices = (const int*)d_in[0];
    const float* eps     = (const float*)d_in[1];
    float*       out     = (float*)d_out;

    const size_t need = (size_t)2 * N_DIM * L_DIM * sizeof(float);  // 4 MB
    if (ws_size >= need) {
        float* epsT = (float*)d_ws;
        dim3 tgrid(L_DIM / 32, N_DIM / 32, 2);
        transpose_eps<<<tgrid, dim3(32, 8), 0, stream>>>(eps, epsT);
        arqgps_lds4<<<B_DIM / 16, 256, 0, stream>>>(indices, epsT, out);
    } else {
        arqgps_fallback<<<B_DIM / 16, 512, 0, stream>>>(indices, eps, out);
    }
}

// Round 10
// 43.318 us; speedup vs baseline: 1.3086x; 1.3086x over previous
//
#include <hip/hip_runtime.h>
#include <math.h>

#define B_DIM 4096
#define L_DIM 512
#define N_DIM 1024

// -half*log(2): exact value of each term once P has fully underflowed to zero.
#define NEG_HALF_LOG2 (-0.34657359027997264f)

typedef float f32x2 __attribute__((ext_vector_type(2)));
typedef float f32x4 __attribute__((ext_vector_type(4)));
typedef unsigned int u32;
typedef u32 u32x2 __attribute__((ext_vector_type(2)));
typedef u32 u32x4 __attribute__((ext_vector_type(4)));

// Select component k (compile-time) of an 8-index chunk held in two int4s.
#define SEL8(k, A, B) ((k) == 0 ? (A).x : (k) == 1 ? (A).y : (k) == 2 ? (A).z \
                     : (k) == 3 ? (A).w : (k) == 4 ? (B).x : (k) == 5 ? (B).y \
                     : (k) == 6 ? (B).z : (B).w)

// ---------------------------------------------------------------------------
// Packed fp32 ops (VOP3P), 2x the scalar v_fma_f32 rate on CDNA4.
// ---------------------------------------------------------------------------
__device__ __forceinline__ f32x2 pk_fma(f32x2 a, f32x2 b, f32x2 c) {
    f32x2 d;
    asm("v_pk_fma_f32 %0, %1, %2, %3" : "=v"(d) : "v"(a), "v"(b), "v"(c));
    return d;
}
__device__ __forceinline__ f32x2 pk_mul(f32x2 a, f32x2 b) {
    f32x2 d;
    asm("v_pk_mul_f32 %0, %1, %2" : "=v"(d) : "v"(a), "v"(b));
    return d;
}
__device__ __forceinline__ f32x2 pk_add(f32x2 a, f32x2 b) {
    f32x2 d;
    asm("v_pk_add_f32 %0, %1, %2" : "=v"(d) : "v"(a), "v"(b));
    return d;
}

// bf16 (round-to-nearest-even) conversion helpers.
__device__ __forceinline__ unsigned short f2bf(float f) {
    u32 u = __float_as_uint(f);
    u32 r = (u + 0x7fffu + ((u >> 16) & 1u)) >> 16;
    return (unsigned short)r;
}
// One u32 holds two bf16 (n0 = low16, n1 = high16) -> f32x2 {n0, n1}.
__device__ __forceinline__ f32x2 bf2f(u32 u) {
    f32x2 r;
    r.x = __uint_as_float(u << 16);
    r.y = __uint_as_float(u & 0xffff0000u);
    return r;
}

// ---------------------------------------------------------------------------
// Kernel A: transpose eps (2, N, L) f32 -> epsTb (L, 2, N) bf16.
// ---------------------------------------------------------------------------
__global__ void transpose_eps_bf16(const float* __restrict__ eps,
                                   unsigned short* __restrict__ epsTb) {
    __shared__ float tile[32][33];
    const int s  = blockIdx.z;
    const int i0 = blockIdx.x * 32;
    const int n0 = blockIdx.y * 32;
    const int tx = threadIdx.x;
    const int ty = threadIdx.y;
#pragma unroll
    for (int k = 0; k < 32; k += 8) {
        tile[ty + k][tx] =
            eps[((size_t)s * N_DIM + (size_t)(n0 + ty + k)) * L_DIM + (i0 + tx)];
    }
    __syncthreads();
#pragma unroll
    for (int k = 0; k < 32; k += 8) {
        epsTb[(size_t)(i0 + ty + k) * (2 * N_DIM) + (size_t)s * N_DIM + (n0 + tx)] =
            f2bf(tile[tx][ty + k]);
    }
}

// ---------------------------------------------------------------------------
// DPP wave-64 sum; lane 63 ends with the full sum. All VALU-pipe.
// ---------------------------------------------------------------------------
template <int CTRL>
__device__ __forceinline__ float dpp_add(float x) {
    int v = __builtin_amdgcn_update_dpp(0, __float_as_int(x), CTRL, 0xf, 0xf, true);
    return x + __int_as_float(v);
}
__device__ __forceinline__ float wave_sum63(float x) {
    x = dpp_add<0x111>(x);  // row_shr:1
    x = dpp_add<0x112>(x);  // row_shr:2
    x = dpp_add<0x114>(x);  // row_shr:4
    x = dpp_add<0x118>(x);  // row_shr:8
    x = dpp_add<0x142>(x);  // row_bcast:15
    x = dpp_add<0x143>(x);  // row_bcast:31
    return x;
}
__device__ __forceinline__ float read63(float x) {
    return __int_as_float(__builtin_amdgcn_readlane(__float_as_int(x), 63));
}

// ---------------------------------------------------------------------------
// Main kernel: 512 threads = 8 waves, R=2 rows/wave (16 rows/block, 256
// blocks = 1/CU, 2 waves/SIMD — the r9 lesson: TLP is mandatory).
// eps slices live in LDS as bf16 (4 KB/slice): both slices = 4 ds_read_b128
// per lane per step (half of r8's 8 — LDS pipe was the biggest term).
// Two 8-slice LDS banks; chunk c computes from bank p while reg-staging the
// next chunk's 8 slices into bank p^1; the per-chunk __syncthreads_or vote
// is the ONLY barrier (1 per 8 steps vs r8's 1 per step).
// P stays f32; bf16 quantization is common to x0/x1 so xs-m cancels it.
// ---------------------------------------------------------------------------
__global__ __launch_bounds__(512, 2) void arqgps_bf16(
    const int* __restrict__ indices,
    const unsigned short* __restrict__ epsTb,   // (L, 2, N) bf16
    float* __restrict__ out)
{
    const int tid  = threadIdx.x;
    const int lane = tid & 63;
    const int wave = __builtin_amdgcn_readfirstlane(tid >> 6);
    const int b0   = blockIdx.x * 16 + wave * 2;
    const int b1   = b0 + 1;
    const int* idx0 = indices + (size_t)b0 * L_DIM;
    const int* idx1 = indices + (size_t)b1 * L_DIM;

    // 2 banks x 8 slices x 4 KB = 64 KB.
    __shared__ unsigned short sbuf[2][8][2 * N_DIM];

    const u32* gsrc = (const u32*)epsTb;   // 1024 u32 per slice

    // Prime: slices 0..7 -> bank 0 (each thread 8 B per slice).
#pragma unroll
    for (int k = 0; k < 8; ++k) {
        u32x2 v = *(const u32x2*)(gsrc + (size_t)k * 1024 + tid * 2);
        *(u32x2*)((u32*)&sbuf[0][k][0] + tid * 2) = v;
    }
    __syncthreads();

    f32x2 P0[8], P1[8];
#pragma unroll
    for (int t = 0; t < 8; ++t) {
        P0[t] = (f32x2){1.0f, 1.0f};
        P1[t] = (f32x2){1.0f, 1.0f};
    }

    float vacc = 0.0f;   // batched-tail accumulator (lanes 0..15 live)
    float uacc = 0.0f;   // uniform early-exit remainder
    float collA = 0.0f, collB = 0.0f;

    for (int i0 = 0; i0 < L_DIM; i0 += 8) {
        const int p = (i0 >> 3) & 1;

        const int4 sA0 = *(const int4*)(idx0 + i0);
        const int4 sB0 = *(const int4*)(idx0 + i0 + 4);
        const int4 sA1 = *(const int4*)(idx1 + i0);
        const int4 sB1 = *(const int4*)(idx1 + i0 + 4);

        // Stage next chunk's slices in registers (two groups of 4 to bound
        // liveness); committed to bank p^1 after the compute loop.
        u32x2 stg[8];
#pragma unroll
        for (int k = 0; k < 4; ++k) {
            int sl = i0 + 8 + k; sl = (sl < L_DIM) ? sl : (L_DIM - 1);
            stg[k] = *(const u32x2*)(gsrc + (size_t)sl * 1024 + tid * 2);
        }

        int sm0 = 0, sm1 = 0;
#pragma unroll
        for (int k = 0; k < 8; ++k) {
            if (k == 4) {
#pragma unroll
                for (int kk = 4; kk < 8; ++kk) {
                    int sl = i0 + 8 + kk; sl = (sl < L_DIM) ? sl : (L_DIM - 1);
                    stg[kk] = *(const u32x2*)(gsrc + (size_t)sl * 1024 + tid * 2);
                }
            }

            // Both slices, bf16: 4 x ds_read_b128 per lane.
            const u32* slp = (const u32*)&sbuf[p][k][0];
            const u32x4 q0a = *(const u32x4*)(slp + lane * 4);          // s=0, n=lane*8..
            const u32x4 q0b = *(const u32x4*)(slp + 256 + lane * 4);    // s=0, n=512+lane*8..
            const u32x4 q1a = *(const u32x4*)(slp + 512 + lane * 4);    // s=1
            const u32x4 q1b = *(const u32x4*)(slp + 768 + lane * 4);

            // Unpack to f32 pairs. E index t: t<4 -> n=lane*8+2t, t>=4 -> n=512+lane*8+2(t-4).
            f32x2 E0[8], E1[8];
#pragma unroll
            for (int j = 0; j < 4; ++j) {
                E0[j]     = bf2f(q0a[j]);
                E0[4 + j] = bf2f(q0b[j]);
                E1[j]     = bf2f(q1a[j]);
                E1[4 + j] = bf2f(q1b[j]);
            }

            // Dots: 2 rows x 2 slices, 2 accumulators each for ILP.
            f32x2 d00 = {0.f, 0.f}, d01 = {0.f, 0.f};   // row0, slice0
            f32x2 d10 = {0.f, 0.f}, d11 = {0.f, 0.f};   // row0, slice1
            f32x2 d20 = {0.f, 0.f}, d21 = {0.f, 0.f};   // row1, slice0
            f32x2 d30 = {0.f, 0.f}, d31 = {0.f, 0.f};   // row1, slice1
#pragma unroll
            for (int t = 0; t < 8; t += 2) {
                d00 = pk_fma(E0[t],     P0[t],     d00);
                d01 = pk_fma(E0[t + 1], P0[t + 1], d01);
                d10 = pk_fma(E1[t],     P0[t],     d10);
                d11 = pk_fma(E1[t + 1], P0[t + 1], d11);
                d20 = pk_fma(E0[t],     P1[t],     d20);
                d21 = pk_fma(E0[t + 1], P1[t + 1], d21);
                d30 = pk_fma(E1[t],     P1[t],     d30);
                d31 = pk_fma(E1[t + 1], P1[t + 1], d31);
            }
            const f32x2 s00 = pk_add(d00, d01);
            const f32x2 s01 = pk_add(d10, d11);
            const f32x2 s10 = pk_add(d20, d21);
            const f32x2 s11 = pk_add(d30, d31);
            const float X00 = read63(wave_sum63(s00.x + s00.y));   // row0 x0
            const float X01 = read63(wave_sum63(s01.x + s01.y));   // row0 x1
            const float X10 = read63(wave_sum63(s10.x + s10.y));   // row1 x0
            const float X11 = read63(wave_sum63(s11.x + s11.y));   // row1 x1

            // Collect: row0 step k -> lane k; row1 step k -> lane 8+k.
            const bool isk0 = (lane == k);
            const bool isk1 = (lane == k + 8);
            collA = isk0 ? X00 : (isk1 ? X10 : collA);
            collB = isk0 ? X01 : (isk1 ? X11 : collB);

            const int s0 = __builtin_amdgcn_readfirstlane(SEL8(k, sA0, sB0));
            const int s1 = __builtin_amdgcn_readfirstlane(SEL8(k, sA1, sB1));
            sm0 |= (s0 << k);
            sm1 |= (s1 << k);

            // P updates under wave-uniform scalar branches.
            if (s0) {
#pragma unroll
                for (int t = 0; t < 8; ++t) P0[t] = pk_mul(P0[t], E1[t]);
            } else {
#pragma unroll
                for (int t = 0; t < 8; ++t) P0[t] = pk_mul(P0[t], E0[t]);
            }
            if (s1) {
#pragma unroll
                for (int t = 0; t < 8; ++t) P1[t] = pk_mul(P1[t], E1[t]);
            } else {
#pragma unroll
                for (int t = 0; t < 8; ++t) P1[t] = pk_mul(P1[t], E0[t]);
            }
        }

        // Commit staged slices into the other bank (reads of bank p^1 all
        // completed before the PREVIOUS chunk's vote barrier).
        {
            u32* dst = (u32*)&sbuf[p ^ 1][0][0];
#pragma unroll
            for (int k = 0; k < 8; ++k)
                *(u32x2*)(dst + (size_t)k * 1024 + tid * 2) = stg[k];
        }

        // Batched tail: lane k -> row0 step i0+k; lane 8+k -> row1 step i0+k.
        {
            const float Av = collA, Bv = collB;
            const int   kk = lane & 7;
            const int   sm = (lane < 8) ? sm0 : sm1;
            const int   sb = (sm >> kk) & 1;
            const float xs = sb ? Bv : Av;
            const float m  = fmaxf(Av, Bv);
            const float d  = fabsf(Av - Bv);
            const float c  = (xs - m) - 0.5f * __logf(1.0f + __expf(-2.0f * d));
            vacc += (lane < 16) ? c : 0.0f;
        }

        // Vote doubles as the chunk barrier (writes above -> visible after).
        float mx = 0.f;
#pragma unroll
        for (int t = 0; t < 8; ++t) {
            mx = fmaxf(mx, fmaxf(fabsf(P0[t].x), fabsf(P0[t].y)));
            mx = fmaxf(mx, fmaxf(fabsf(P1[t].x), fabsf(P1[t].y)));
        }
        if (!__syncthreads_or(mx > 0.0f)) {
            uacc = (float)(L_DIM - 8 - i0) * NEG_HALF_LOG2;
            break;
        }
    }

    // Per-row sums: butterfly within each 8-lane group (xor 1,2,4).
    float s = vacc;
    s += __shfl_xor(s, 1, 64);
    s += __shfl_xor(s, 2, 64);
    s += __shfl_xor(s, 4, 64);
    if (lane == 0) out[b0] = s + uacc;
    if (lane == 8) out[b1] = s + uacc;
}

// ---------------------------------------------------------------------------
// Fallback (no workspace): round-7/8 per-wave kernel reading eps strided.
// ---------------------------------------------------------------------------
__global__ __launch_bounds__(512, 2) void arqgps_fallback(
    const int* __restrict__ indices,
    const float* __restrict__ eps,    // (2, N, L)
    float* __restrict__ out)
{
    const int lane  = threadIdx.x & 63;
    const int wave  = __builtin_amdgcn_readfirstlane((int)(threadIdx.x >> 6));
    const int b0    = (blockIdx.x * 8 + wave) * 2;
    const int b1    = b0 + 1;
    const int lane4 = lane * 4;
    const int* idx0 = indices + (size_t)b0 * L_DIM;
    const int* idx1 = indices + (size_t)b1 * L_DIM;

    f32x2 P0[8], P1[8];
#pragma unroll
    for (int c = 0; c < 8; ++c) {
        P0[c] = (f32x2){1.0f, 1.0f};
        P1[c] = (f32x2){1.0f, 1.0f};
    }
    float vacc = 0.0f, uacc = 0.0f, collA = 0.0f, collB = 0.0f;

    for (int i0 = 0; i0 < L_DIM; i0 += 8) {
        const int4 sA0 = *(const int4*)(idx0 + i0);
        const int4 sB0 = *(const int4*)(idx0 + i0 + 4);
        const int4 sA1 = *(const int4*)(idx1 + i0);
        const int4 sB1 = *(const int4*)(idx1 + i0 + 4);
        int smask0 = 0, smask1 = 0;
#pragma unroll
        for (int k = 0; k < 8; ++k) {
            const int i = i0 + k;
            f32x4 e0q[4], e1q[4];
#pragma unroll
            for (int c = 0; c < 4; ++c) {
                const int n = c * 256 + lane4;
                f32x4 t0, t1;
#pragma unroll
                for (int j = 0; j < 4; ++j) {
                    t0[j] = eps[(size_t)(n + j) * L_DIM + i];
                    t1[j] = eps[((size_t)N_DIM + n + j) * L_DIM + i];
                }
                e0q[c] = t0; e1q[c] = t1;
            }
            f32x2 a00 = {0.f, 0.f}, a01 = {0.f, 0.f};
            f32x2 a10 = {0.f, 0.f}, a11 = {0.f, 0.f};
            f32x2 c00 = {0.f, 0.f}, c01 = {0.f, 0.f};
            f32x2 c10 = {0.f, 0.f}, c11 = {0.f, 0.f};
#pragma unroll
            for (int c = 0; c < 4; ++c) {
                const f32x2 lo0 = __builtin_shufflevector(e0q[c], e0q[c], 0, 1);
                const f32x2 hi0 = __builtin_shufflevector(e0q[c], e0q[c], 2, 3);
                const f32x2 lo1 = __builtin_shufflevector(e1q[c], e1q[c], 0, 1);
                const f32x2 hi1 = __builtin_shufflevector(e1q[c], e1q[c], 2, 3);
                a00 = pk_fma(lo0, P0[2 * c],     a00);
                a01 = pk_fma(hi0, P0[2 * c + 1], a01);
                a10 = pk_fma(lo1, P0[2 * c],     a10);
                a11 = pk_fma(hi1, P0[2 * c + 1], a11);
                c00 = pk_fma(lo0, P1[2 * c],     c00);
                c01 = pk_fma(hi0, P1[2 * c + 1], c01);
                c10 = pk_fma(lo1, P1[2 * c],     c10);
                c11 = pk_fma(hi1, P1[2 * c + 1], c11);
            }
            const f32x2 r0x0 = pk_add(a00, a01);
            const f32x2 r0x1 = pk_add(a10, a11);
            const f32x2 r1x0 = pk_add(c00, c01);
            const f32x2 r1x1 = pk_add(c10, c11);
            const float X00 = read63(wave_sum63(r0x0.x + r0x0.y));
            const float X01 = read63(wave_sum63(r0x1.x + r0x1.y));
            const float X10 = read63(wave_sum63(r1x0.x + r1x0.y));
            const float X11 = read63(wave_sum63(r1x1.x + r1x1.y));
            const bool isk0 = (lane == k);
            const bool isk1 = (lane == k + 8);
            collA = isk0 ? X00 : (isk1 ? X10 : collA);
            collB = isk0 ? X01 : (isk1 ? X11 : collB);
            const int s0 = __builtin_amdgcn_readfirstlane(SEL8(k, sA0, sB0));
            const int s1 = __builtin_amdgcn_readfirstlane(SEL8(k, sA1, sB1));
            smask0 |= (s0 << k);
            smask1 |= (s1 << k);
            if (s0) {
#pragma unroll
                for (int c = 0; c < 8; ++c)
                    P0[c] = pk_mul(P0[c], (c & 1) ?
                        __builtin_shufflevector(e1q[c >> 1], e1q[c >> 1], 2, 3) :
                        __builtin_shufflevector(e1q[c >> 1], e1q[c >> 1], 0, 1));
            } else {
#pragma unroll
                for (int c = 0; c < 8; ++c)
                    P0[c] = pk_mul(P0[c], (c & 1) ?
                        __builtin_shufflevector(e0q[c >> 1], e0q[c >> 1], 2, 3) :
                        __builtin_shufflevector(e0q[c >> 1], e0q[c >> 1], 0, 1));
            }
            if (s1) {
#pragma unroll
                for (int c = 0; c < 8; ++c)
                    P1[c] = pk_mul(P1[c], (c & 1) ?
                        __builtin_shufflevector(e1q[c >> 1], e1q[c >> 1], 2, 3) :
                        __builtin_shufflevector(e1q[c >> 1], e1q[c >> 1], 0, 1));
            } else {
#pragma unroll
                for (int c = 0; c < 8; ++c)
                    P1[c] = pk_mul(P1[c], (c & 1) ?
                        __builtin_shufflevector(e0q[c >> 1], e0q[c >> 1], 2, 3) :
                        __builtin_shufflevector(e0q[c >> 1], e0q[c >> 1], 0, 1));
            }
        }
        {
            const float Av = collA, Bv = collB;
            const int   kk = lane & 7;
            const int   sm = (lane < 8) ? smask0 : smask1;
            const int   sb = (sm >> kk) & 1;
            const float xs = sb ? Bv : Av;
            const float m  = fmaxf(Av, Bv);
            const float d  = fabsf(Av - Bv);
            const float c  = (xs - m) - 0.5f * __logf(1.0f + __expf(-2.0f * d));
            vacc += (lane < 16) ? c : 0.0f;
        }
        float mx = 0.f;
#pragma unroll
        for (int c = 0; c < 8; ++c) {
            mx = fmaxf(mx, fmaxf(fabsf(P0[c].x), fabsf(P0[c].y)));
            mx = fmaxf(mx, fmaxf(fabsf(P1[c].x), fabsf(P1[c].y)));
        }
        if (!__any(mx > 0.0f)) {
            uacc = (float)(L_DIM - 8 - i0) * NEG_HALF_LOG2;
            break;
        }
    }
    float s = vacc;
    s += __shfl_xor(s, 1, 64);
    s += __shfl_xor(s, 2, 64);
    s += __shfl_xor(s, 4, 64);
    if (lane == 0) out[b0] = s + uacc;
    if (lane == 8) out[b1] = s + uacc;
}

extern "C" void kernel_launch(void* const* d_in, const int* in_sizes, int n_in,
                              void* d_out, int out_size, void* d_ws, size_t ws_size,
                              hipStream_t stream) {
    const int*   indices = (const int*)d_in[0];
    const float* eps     = (const float*)d_in[1];
    float*       out     = (float*)d_out;

    const size_t need = (size_t)L_DIM * 2 * N_DIM * sizeof(unsigned short); // 2 MB
    if (ws_size >= need) {
        unsigned short* epsTb = (unsigned short*)d_ws;
        dim3 tgrid(L_DIM / 32, N_DIM / 32, 2);
        transpose_eps_bf16<<<tgrid, dim3(32, 8), 0, stream>>>(eps, epsTb);
        arqgps_bf16<<<B_DIM / 16, 512, 0, stream>>>(indices, epsTb, out);
    } else {
        arqgps_fallback<<<B_DIM / 16, 512, 0, stream>>>(indices, eps, out);
    }
}